// Round 6
// baseline (688.827 us; speedup 1.0000x reference)
//
#include <hip/hip_runtime.h>
#include <stdint.h>

#define BATCH 256
#define IN_F  1024
#define OUT_F 1024
#define RT    16      // row tiles (IN_F/64)
#define STN   16      // input bit-streams
#define NCOL  16384   // 16 (sg,s) groups * 1024 outputs

typedef int   v4i  __attribute__((ext_vector_type(4)));
typedef int   v16i __attribute__((ext_vector_type(16)));
typedef float v2f  __attribute__((ext_vector_type(2)));

// ws layout: Ap2 4MB | Bp 16MB | Part 16MB | flags 512B
#define AP_SZ   ((size_t)STN * BATCH * IN_F)
#define BP_SZ   ((size_t)64 * NCOL * 16)
#define PART_SZ ((size_t)16 * BATCH * OUT_F * sizeof(float))

// ---------------------------------------------------------------------------
// Fused prep.  Blocks 0..255: pack_B (one item per (g,o); writes 16 sgs slice
// vectors + nonzero flags).  Blocks 256..319: pack_A into per-(r,y) 32KB
// windows: chunk ((r*8+y)*16+t) of 2048B = {f=0 1KB, f=1 1KB}, lane l=hi*32+
// (b&31) holds 16 bytes.  cim reads all 16 t of one (r,y) via one base +
// t*2048 offsets (deep prefetch friendly).
// ---------------------------------------------------------------------------
__global__ __launch_bounds__(256) void pack_fused(
    const float* __restrict__ x, const float* __restrict__ w,
    uint8_t* __restrict__ Ap2, uint8_t* __restrict__ Bp,
    uint32_t* __restrict__ flags)
{
    if (blockIdx.x < 256) {
        // ---------------- pack_B ----------------
        int item = blockIdx.x * 256 + threadIdx.x;      // 65536 items
        int o = item & 1023;
        int g = item >> 10;                             // 0..63
        const float* wr = w + (size_t)o * IN_F + g * 16;
        uint32_t wq[2][16];
        #pragma unroll
        for (int j = 0; j < 16; ++j) {
            float wv = wr[j];
            float wp = rintf(fmaxf(wv, 0.0f) * 4096.0f);
            float wn = rintf(fmaxf(-wv, 0.0f) * 4096.0f);
            wq[0][j] = (uint32_t)fminf(wp, 65535.0f);
            wq[1][j] = (uint32_t)fminf(wn, 65535.0f);
        }
        uint32_t nzmask = 0;
        #pragma unroll
        for (int sgs = 0; sgs < 16; ++sgs) {
            int sg = sgs >> 3, sh = 14 - 2 * (sgs & 7);
            uint32_t dw[4], nz = 0;
            #pragma unroll
            for (int q = 0; q < 4; ++q) {
                uint32_t d = 0;
                #pragma unroll
                for (int j = 0; j < 4; ++j)
                    d |= ((wq[sg][q * 4 + j] >> sh) & 3u) << (8 * j);
                dw[q] = d;
                nz |= d;
            }
            *(uint4*)(Bp + (size_t)(g * NCOL + sgs * 1024 + o) * 16) =
                make_uint4(dw[0], dw[1], dw[2], dw[3]);
            nzmask |= (nz ? 1u : 0u) << sgs;
        }
        int r = g >> 2, ob = o >> 7;                    // wave-uniform
        #pragma unroll
        for (int sgs = 0; sgs < 16; ++sgs) {
            int any = __any((int)((nzmask >> sgs) & 1u));
            if (any && (threadIdx.x & 63) == 0)
                atomicOr(&flags[sgs * 8 + ob], 1u << r);
        }
    } else {
        // ---------------- pack_A ----------------
        int item = (blockIdx.x - 256) * 256 + threadIdx.x;  // 16384 items
        int b  = item & 255;
        int kg = item >> 8;                             // 0..63
        int r = kg >> 2, f = (kg >> 1) & 1, hi = kg & 1;
        int y = b >> 5, l = hi * 32 + (b & 31);
        const float* xr = x + (size_t)b * IN_F + kg * 16;
        uint32_t xu[16];
        #pragma unroll
        for (int j = 0; j < 16; ++j) {
            float xf = rintf(xr[j] * 4096.0f);          // round half-even
            xf = fminf(fmaxf(xf, -32768.0f), 32767.0f);
            xu[j] = (uint32_t)((int)xf) & 0xFFFFu;      // two's complement
        }
        #pragma unroll
        for (int t = 0; t < STN; ++t) {
            uint32_t dw[4];
            #pragma unroll
            for (int q = 0; q < 4; ++q) {
                uint32_t d = 0;
                #pragma unroll
                for (int j = 0; j < 4; ++j)
                    d |= ((xu[q * 4 + j] >> t) & 1u) << (8 * j);
                dw[q] = d;
            }
            *(uint4*)(Ap2 + ((size_t)((r * 8 + y) * 16 + t)) * 2048
                          + f * 1024 + l * 16) =
                make_uint4(dw[0], dw[1], dw[2], dw[3]);
        }
    }
}

// ---------------------------------------------------------------------------
// Main.  blockIdx.x -> active (sgs,ob) pair ranked by DESCENDING r-popcount
// (LPT: longest blocks dispatch first), deterministic ballot bucket scan.
// t-loop: depth-4 register double-buffer prefetch of A fragments (static
// ring indices).  ADC bits identical to verified R1-R5.
// ---------------------------------------------------------------------------
__global__ __launch_bounds__(256, 4) void cim_mfma(
    const uint8_t* __restrict__ Ap2, const uint8_t* __restrict__ Bp,
    const uint32_t* __restrict__ flags, float* __restrict__ part)
{
    const float MAG = 12582912.0f;                  // 2^23 + 2^22
    int tid = threadIdx.x, wid = tid >> 6, l = tid & 63, h2 = l >> 5;

    // ---- LPT worklist: rank pairs by (popcount desc, index asc) ----
    uint32_t f0 = flags[l], f1 = flags[64 + l];
    int pc0 = __popc(f0), pc1 = __popc(f1);
    int total = __popcll(__ballot(pc0 > 0)) + __popcll(__ballot(pc1 > 0));
    int idx = blockIdx.x;
    if (idx >= total) return;
    unsigned long long lt = (1ULL << l) - 1;
    int rank0 = 0, rank1 = 0;
    #pragma unroll
    for (int v = 16; v >= 1; --v) {
        unsigned long long m0 = __ballot(pc0 == v);
        unsigned long long m1 = __ballot(pc1 == v);
        int c = __popcll(m0) + __popcll(m1);
        rank0 += (pc0 < v) ? c : ((pc0 == v) ? __popcll(m0 & lt) : 0);
        rank1 += (pc1 < v) ? c : ((pc1 == v) ? (__popcll(m0) + __popcll(m1 & lt)) : 0);
    }
    unsigned long long s0 = __ballot(rank0 == idx);
    unsigned long long s1 = __ballot(rank1 == idx);
    int p = s0 ? __builtin_ctzll(s0) : (64 + __builtin_ctzll(s1));
    int sgs = p >> 3, ob = p & 7;
    uint32_t fb = flags[p];

    int y = blockIdx.y;
    int s = sgs & 7, sg = sgs >> 3;
    int col = sgs * 1024 + ob * 128 + wid * 32 + (l & 31);
    float clane = ldexpf(192.0f / 255.0f, 14 - 2 * s);   // step * 4^(7-s)
    if (sg) clane = -clane;

    v2f acc2[8];
    #pragma unroll
    for (int i = 0; i < 8; ++i) acc2[i] = (v2f)0.0f;
    v16i zero;
    #pragma unroll
    for (int i = 0; i < 16; ++i) zero[i] = 0;

    for (int r = 0; r < RT; ++r) {
        if (!((fb >> r) & 1u)) continue;            // uniform skip, exact

        v4i bf0 = *(const v4i*)(Bp + ((size_t)(r * 4 + h2)     * NCOL + col) * 16);
        v4i bf1 = *(const v4i*)(Bp + ((size_t)(r * 4 + 2 + h2) * NCOL + col) * 16);

        const uint8_t* abase = Ap2 + ((size_t)(r * 8 + y) * 16) * 2048 + l * 16;

        // depth-4 register prefetch ring (static indices after unroll)
        v4i A0[4], A1[4];
        #pragma unroll
        for (int pt = 0; pt < 4; ++pt) {
            A0[pt] = *(const v4i*)(abase + pt * 2048);
            A1[pt] = *(const v4i*)(abase + pt * 2048 + 1024);
        }
        #pragma unroll
        for (int t = 0; t < STN; ++t) {
            v4i af0 = A0[t & 3], af1 = A1[t & 3];
            if (t < STN - 4) {
                A0[t & 3] = *(const v4i*)(abase + (t + 4) * 2048);
                A1[t & 3] = *(const v4i*)(abase + (t + 4) * 2048 + 1024);
            }
            v16i c = __builtin_amdgcn_mfma_i32_32x32x32_i8(af0, bf0, zero, 0, 0, 0);
            c      = __builtin_amdgcn_mfma_i32_32x32x32_i8(af1, bf1, c,    0, 0, 0);
            float wt = (t == 15) ? -32768.0f : (float)(1 << t);
            float cw = clane * wt;                  // exact pow2 scale
            #pragma unroll
            for (int i = 0; i < 8; ++i) {
                v2f af; af.x = (float)c[2 * i]; af.y = (float)c[2 * i + 1];
                v2f tq;
                tq.x = fmaf(af.x, 1.328125f, MAG);  // exact product; add rounds
                tq.y = fmaf(af.y, 1.328125f, MAG);  //   half-even == rintf
                v2f qf = tq - MAG;                  // Sterbenz-exact
                acc2[i].x = fmaf(qf.x, cw, acc2[i].x);
                acc2[i].y = fmaf(qf.y, cw, acc2[i].y);
            }
        }
    }

    int o = ob * 128 + wid * 32 + (l & 31);
    #pragma unroll
    for (int i = 0; i < 16; ++i) {
        int b = y * 32 + (i & 3) + 8 * (i >> 2) + 4 * h2;   // C/D row map
        float v = (i & 1) ? acc2[i >> 1].y : acc2[i >> 1].x;
        part[((size_t)sgs * BATCH + b) * OUT_F + o] = v;
    }
}

// ---------------------------------------------------------------------------
// Final reduce: sums only flagged (sgs,ob) Part slots (unflagged slots were
// never written; their exact contribution is 0).
// ---------------------------------------------------------------------------
__global__ __launch_bounds__(256) void reduce_out(
    const float* __restrict__ part, const uint32_t* __restrict__ flags,
    const float* __restrict__ bias, float* __restrict__ out)
{
    int idx = blockIdx.x * 256 + threadIdx.x;
    int o = idx & (OUT_F - 1), b = idx >> 10;
    int ob = o >> 7;
    float ov = 0.0f;
    #pragma unroll
    for (int sgs = 0; sgs < 16; ++sgs) {
        if (flags[sgs * 8 + ob])
            ov += part[((size_t)sgs * BATCH + b) * OUT_F + o];
    }
    ov *= 0x1p-24f;
    float q = rintf(ov * 4096.0f);
    q = fminf(fmaxf(q, -32768.0f), 32767.0f);
    out[idx] = q * 0x1p-12f + bias[o];
}

// ---------------------------------------------------------------------------
extern "C" void kernel_launch(void* const* d_in, const int* in_sizes, int n_in,
                              void* d_out, int out_size, void* d_ws, size_t ws_size,
                              hipStream_t stream) {
    const float* x    = (const float*)d_in[0];
    const float* w    = (const float*)d_in[1];
    const float* bias = (const float*)d_in[2];
    float* out = (float*)d_out;

    uint8_t*  Ap2   = (uint8_t*)d_ws;
    uint8_t*  Bp    = Ap2 + AP_SZ;
    float*    Part  = (float*)(Bp + BP_SZ);
    uint32_t* flags = (uint32_t*)((uint8_t*)Part + PART_SZ);

    hipMemsetAsync(flags, 0, 128 * sizeof(uint32_t), stream);
    hipLaunchKernelGGL(pack_fused, dim3(320), dim3(256), 0, stream,
                       x, w, Ap2, Bp, flags);
    hipLaunchKernelGGL(cim_mfma, dim3(128, 8), dim3(256), 0, stream,
                       Ap2, Bp, flags, Part);
    hipLaunchKernelGGL(reduce_out, dim3(BATCH * OUT_F / 256), dim3(256), 0, stream,
                       Part, flags, bias, out);
}

// Round 7
// 185.199 us; speedup vs baseline: 3.7194x; 3.7194x over previous
//
#include <hip/hip_runtime.h>
#include <stdint.h>

#define BATCH 256
#define IN_F  1024
#define OUT_F 1024
#define RT    16      // row tiles (IN_F/64)
#define STN   16      // input bit-streams
#define NCOL  16384   // 16 (sg,s) groups * 1024 outputs

typedef int v4i  __attribute__((ext_vector_type(4)));
typedef int v16i __attribute__((ext_vector_type(16)));

// ws layout: Ap2 4MB | Bp 16MB | flags 512B
#define AP_SZ ((size_t)STN * BATCH * IN_F)
#define BP_SZ ((size_t)64 * NCOL * 16)

// ---------------------------------------------------------------------------
// Fused prep.
// Blocks 0..511: pack_B, item = ((g*2+sg)*1024+o): quantize one sign of
//   w[o][g*16..+16], emit 8 slice vectors (coalesced 1KB/wave stores) and
//   per-(sgs,ob) nonzero flags (bit r).
// Blocks 512..767: pack_A, item = (kg, tq, b): quantize x[b][kg*16..+16],
//   emit 4 t-planes into the per-(r,y) 32KB window layout:
//   addr = (r*8+y)*32768 + t*2048 + f*1024 + l*16, l = hi*32 + (b&31).
// ---------------------------------------------------------------------------
__global__ __launch_bounds__(256) void pack_fused(
    const float* __restrict__ x, const float* __restrict__ w,
    uint8_t* __restrict__ Ap2, uint8_t* __restrict__ Bp,
    uint32_t* __restrict__ flags)
{
    if (blockIdx.x < 512) {
        // ---------------- pack_B (one sign per item) ----------------
        int item = blockIdx.x * 256 + threadIdx.x;      // 131072 items
        int o  = item & 1023;
        int sg = (item >> 10) & 1;
        int g  = item >> 11;                            // 0..63
        const float* wr = w + (size_t)o * IN_F + g * 16;
        uint32_t wq[16];
        #pragma unroll
        for (int j = 0; j < 16; ++j) {
            float wv = wr[j];
            float wf = rintf(fmaxf(sg ? -wv : wv, 0.0f) * 4096.0f);
            wq[j] = (uint32_t)fminf(wf, 65535.0f);
        }
        uint32_t nzmask = 0;
        #pragma unroll
        for (int s = 0; s < 8; ++s) {
            int sh = 14 - 2 * s;
            uint32_t dw[4], nz = 0;
            #pragma unroll
            for (int q = 0; q < 4; ++q) {
                uint32_t d = 0;
                #pragma unroll
                for (int j = 0; j < 4; ++j)
                    d |= ((wq[q * 4 + j] >> sh) & 3u) << (8 * j);
                dw[q] = d;
                nz |= d;
            }
            int sgs = sg * 8 + s;
            *(uint4*)(Bp + (size_t)(g * NCOL + sgs * 1024 + o) * 16) =
                make_uint4(dw[0], dw[1], dw[2], dw[3]);
            nzmask |= (nz ? 1u : 0u) << s;
        }
        int r = g >> 2, ob = o >> 7;                    // wave-uniform
        #pragma unroll
        for (int s = 0; s < 8; ++s) {
            int any = __any((int)((nzmask >> s) & 1u));
            if (any && (threadIdx.x & 63) == 0)
                atomicOr(&flags[(sg * 8 + s) * 8 + ob], 1u << r);
        }
    } else {
        // ---------------- pack_A (4 t-planes per item) ----------------
        int item = (blockIdx.x - 512) * 256 + threadIdx.x;  // 65536 items
        int b  = item & 255;
        int tq = (item >> 8) & 3;
        int kg = item >> 10;                            // 0..63
        int r = kg >> 2, f = (kg >> 1) & 1, hi = kg & 1;
        int y = b >> 5, l = hi * 32 + (b & 31);
        const float* xr = x + (size_t)b * IN_F + kg * 16;
        uint32_t xu[16];
        #pragma unroll
        for (int j = 0; j < 16; ++j) {
            float xf = rintf(xr[j] * 4096.0f);          // round half-even
            xf = fminf(fmaxf(xf, -32768.0f), 32767.0f);
            xu[j] = (uint32_t)((int)xf) & 0xFFFFu;      // two's complement
        }
        uint8_t* wbase = Ap2 + ((size_t)(r * 8 + y) * 16) * 2048 + f * 1024 + l * 16;
        #pragma unroll
        for (int tt = 0; tt < 4; ++tt) {
            int t = tq * 4 + tt;
            uint32_t dw[4];
            #pragma unroll
            for (int q = 0; q < 4; ++q) {
                uint32_t d = 0;
                #pragma unroll
                for (int j = 0; j < 4; ++j)
                    d |= ((xu[q * 4 + j] >> t) & 1u) << (8 * j);
                dw[q] = d;
            }
            *(uint4*)(wbase + t * 2048) = make_uint4(dw[0], dw[1], dw[2], dw[3]);
        }
    }
}

// ---------------------------------------------------------------------------
// Main.  blockIdx.x = idx*2+z: idx -> active (sgs,ob) ranked by DESCENDING
// r-popcount (LPT), z = parity of flagged-r rank handled by this block
// (balanced r-split -> ~2x block parallelism).  No LDS, no Part: partial
// sums atomicAdd'ed into out (pre-zeroed); finalize quantizes in place.
// Loop body identical to verified R5 (ADC bits unchanged).
// ---------------------------------------------------------------------------
__global__ __launch_bounds__(256, 4) void cim_mfma(
    const uint8_t* __restrict__ Ap2, const uint8_t* __restrict__ Bp,
    const uint32_t* __restrict__ flags, float* __restrict__ out)
{
    const float MAG = 12582912.0f;                  // 2^23 + 2^22
    int tid = threadIdx.x, wid = tid >> 6, l = tid & 63, h2 = l >> 5;

    // ---- LPT worklist: rank pairs by (popcount desc, index asc) ----
    uint32_t f0 = flags[l], f1 = flags[64 + l];
    int pc0 = __popc(f0), pc1 = __popc(f1);
    int total = __popcll(__ballot(pc0 > 0)) + __popcll(__ballot(pc1 > 0));
    int idx = blockIdx.x >> 1, z = blockIdx.x & 1;
    if (idx >= total) return;
    unsigned long long lt = (1ULL << l) - 1;
    int rank0 = 0, rank1 = 0;
    #pragma unroll
    for (int v = 16; v >= 1; --v) {
        unsigned long long m0 = __ballot(pc0 == v);
        unsigned long long m1 = __ballot(pc1 == v);
        int c = __popcll(m0) + __popcll(m1);
        rank0 += (pc0 < v) ? c : ((pc0 == v) ? __popcll(m0 & lt) : 0);
        rank1 += (pc1 < v) ? c : ((pc1 == v) ? (__popcll(m0) + __popcll(m1 & lt)) : 0);
    }
    unsigned long long s0 = __ballot(rank0 == idx);
    unsigned long long s1 = __ballot(rank1 == idx);
    int p = s0 ? __builtin_ctzll(s0) : (64 + __builtin_ctzll(s1));
    int sgs = p >> 3, ob = p & 7;
    uint32_t fb = flags[p];

    int y = blockIdx.y;
    int s = sgs & 7, sg = sgs >> 3;
    int col = sgs * 1024 + ob * 128 + wid * 32 + (l & 31);
    float clane = ldexpf(192.0f / 255.0f, 14 - 2 * s);   // step * 4^(7-s)
    if (sg) clane = -clane;

    float acc[16];
    #pragma unroll
    for (int i = 0; i < 16; ++i) acc[i] = 0.0f;
    v16i zero;
    #pragma unroll
    for (int i = 0; i < 16; ++i) zero[i] = 0;

    int rank = 0, nproc = 0;
    for (int r = 0; r < RT; ++r) {
        if (!((fb >> r) & 1u)) continue;            // uniform skip, exact
        if ((rank++ & 1) != z) continue;            // r-split across 2 blocks
        ++nproc;

        v4i bf0 = *(const v4i*)(Bp + ((size_t)(r * 4 + h2)     * NCOL + col) * 16);
        v4i bf1 = *(const v4i*)(Bp + ((size_t)(r * 4 + 2 + h2) * NCOL + col) * 16);

        const uint8_t* abase = Ap2 + ((size_t)(r * 8 + y) * 16) * 2048 + l * 16;
        #pragma unroll 4
        for (int t = 0; t < STN; ++t) {
            const uint8_t* ap = abase + t * 2048;
            v4i af0 = *(const v4i*)ap;              // coalesced 1KB/wave
            v4i af1 = *(const v4i*)(ap + 1024);
            v16i c = __builtin_amdgcn_mfma_i32_32x32x32_i8(af0, bf0, zero, 0, 0, 0);
            c      = __builtin_amdgcn_mfma_i32_32x32x32_i8(af1, bf1, c,    0, 0, 0);
            float wt = (t == 15) ? -32768.0f : (float)(1 << t);
            float cw = clane * wt;                  // exact pow2 scale
            #pragma unroll
            for (int i = 0; i < 16; ++i) {
                float af = (float)c[i];             // v_cvt_f32_i32
                float tq = fmaf(af, 1.328125f, MAG);// exact product; add rounds
                float qf = tq - MAG;                //   half-even == rintf
                acc[i] = fmaf(qf, cw, acc[i]);
            }
        }
    }

    if (nproc == 0) return;                         // contributed nothing
    int o = ob * 128 + wid * 32 + (l & 31);
    #pragma unroll
    for (int i = 0; i < 16; ++i) {
        int b = y * 32 + (i & 3) + 8 * (i >> 2) + 4 * h2;   // C/D row map
        atomicAdd(&out[(size_t)b * OUT_F + o], acc[i]);
    }
}

// ---------------------------------------------------------------------------
// In-place finalize: scale, ACM quantize, add bias.
// ---------------------------------------------------------------------------
__global__ __launch_bounds__(256) void finalize(
    float* __restrict__ out, const float* __restrict__ bias)
{
    int idx = blockIdx.x * 256 + threadIdx.x;
    int o = idx & (OUT_F - 1);
    float ov = out[idx] * 0x1p-24f;
    float q = rintf(ov * 4096.0f);
    q = fminf(fmaxf(q, -32768.0f), 32767.0f);
    out[idx] = q * 0x1p-12f + bias[o];
}

// ---------------------------------------------------------------------------
extern "C" void kernel_launch(void* const* d_in, const int* in_sizes, int n_in,
                              void* d_out, int out_size, void* d_ws, size_t ws_size,
                              hipStream_t stream) {
    const float* x    = (const float*)d_in[0];
    const float* w    = (const float*)d_in[1];
    const float* bias = (const float*)d_in[2];
    float* out = (float*)d_out;

    uint8_t*  Ap2   = (uint8_t*)d_ws;
    uint8_t*  Bp    = Ap2 + AP_SZ;
    uint32_t* flags = (uint32_t*)(Bp + BP_SZ);

    hipMemsetAsync(flags, 0, 128 * sizeof(uint32_t), stream);
    hipMemsetAsync(out, 0, (size_t)BATCH * OUT_F * sizeof(float), stream);
    hipLaunchKernelGGL(pack_fused, dim3(768), dim3(256), 0, stream,
                       x, w, Ap2, Bp, flags);
    hipLaunchKernelGGL(cim_mfma, dim3(256, 8), dim3(256), 0, stream,
                       Ap2, Bp, flags, out);
    hipLaunchKernelGGL(finalize, dim3(BATCH * OUT_F / 256), dim3(256), 0, stream,
                       out, bias);
}

// Round 8
// 180.148 us; speedup vs baseline: 3.8237x; 1.0280x over previous
//
#include <hip/hip_runtime.h>
#include <stdint.h>

#define BATCH 256
#define IN_F  1024
#define OUT_F 1024
#define RT    16      // row tiles (IN_F/64)
#define STN   16      // input bit-streams
#define NCOL  16384   // 16 (sg,s) groups * 1024 outputs

typedef int   v4i  __attribute__((ext_vector_type(4)));
typedef int   v16i __attribute__((ext_vector_type(16)));
typedef float v2f  __attribute__((ext_vector_type(2)));

// ws layout: Ap2 4MB | Bp 16MB | flags 512B
#define AP_SZ ((size_t)STN * BATCH * IN_F)
#define BP_SZ ((size_t)64 * NCOL * 16)

// ---------------------------------------------------------------------------
// Fused prep (identical to verified R7).
// Blocks 0..511: pack_B per (g,sg,o); blocks 512..767: pack_A per (kg,tq,b).
// ---------------------------------------------------------------------------
__global__ __launch_bounds__(256) void pack_fused(
    const float* __restrict__ x, const float* __restrict__ w,
    uint8_t* __restrict__ Ap2, uint8_t* __restrict__ Bp,
    uint32_t* __restrict__ flags)
{
    if (blockIdx.x < 512) {
        int item = blockIdx.x * 256 + threadIdx.x;      // 131072 items
        int o  = item & 1023;
        int sg = (item >> 10) & 1;
        int g  = item >> 11;                            // 0..63
        const float* wr = w + (size_t)o * IN_F + g * 16;
        uint32_t wq[16];
        #pragma unroll
        for (int j = 0; j < 16; ++j) {
            float wv = wr[j];
            float wf = rintf(fmaxf(sg ? -wv : wv, 0.0f) * 4096.0f);
            wq[j] = (uint32_t)fminf(wf, 65535.0f);
        }
        uint32_t nzmask = 0;
        #pragma unroll
        for (int s = 0; s < 8; ++s) {
            int sh = 14 - 2 * s;
            uint32_t dw[4], nz = 0;
            #pragma unroll
            for (int q = 0; q < 4; ++q) {
                uint32_t d = 0;
                #pragma unroll
                for (int j = 0; j < 4; ++j)
                    d |= ((wq[q * 4 + j] >> sh) & 3u) << (8 * j);
                dw[q] = d;
                nz |= d;
            }
            int sgs = sg * 8 + s;
            *(uint4*)(Bp + (size_t)(g * NCOL + sgs * 1024 + o) * 16) =
                make_uint4(dw[0], dw[1], dw[2], dw[3]);
            nzmask |= (nz ? 1u : 0u) << s;
        }
        int r = g >> 2, ob = o >> 7;                    // wave-uniform
        #pragma unroll
        for (int s = 0; s < 8; ++s) {
            int any = __any((int)((nzmask >> s) & 1u));
            if (any && (threadIdx.x & 63) == 0)
                atomicOr(&flags[(sg * 8 + s) * 8 + ob], 1u << r);
        }
    } else {
        int item = (blockIdx.x - 512) * 256 + threadIdx.x;  // 65536 items
        int b  = item & 255;
        int tq = (item >> 8) & 3;
        int kg = item >> 10;                            // 0..63
        int r = kg >> 2, f = (kg >> 1) & 1, hi = kg & 1;
        int y = b >> 5, l = hi * 32 + (b & 31);
        const float* xr = x + (size_t)b * IN_F + kg * 16;
        uint32_t xu[16];
        #pragma unroll
        for (int j = 0; j < 16; ++j) {
            float xf = rintf(xr[j] * 4096.0f);          // round half-even
            xf = fminf(fmaxf(xf, -32768.0f), 32767.0f);
            xu[j] = (uint32_t)((int)xf) & 0xFFFFu;      // two's complement
        }
        uint8_t* wbase = Ap2 + ((size_t)(r * 8 + y) * 16) * 2048 + f * 1024 + l * 16;
        #pragma unroll
        for (int tt = 0; tt < 4; ++tt) {
            int t = tq * 4 + tt;
            uint32_t dw[4];
            #pragma unroll
            for (int q = 0; q < 4; ++q) {
                uint32_t d = 0;
                #pragma unroll
                for (int j = 0; j < 4; ++j)
                    d |= ((xu[q * 4 + j] >> t) & 1u) << (8 * j);
                dw[q] = d;
            }
            *(uint4*)(wbase + t * 2048) = make_uint4(dw[0], dw[1], dw[2], dw[3]);
        }
    }
}

// ---------------------------------------------------------------------------
// Main.  blockIdx.x = idx*4+z: idx -> active (sgs,ob) ranked by DESCENDING
// r-popcount (LPT); z = rank&3 of flagged r handled here (4-way balanced
// split -> dominant pc=16 pairs give exactly 4 tuples/block).  Partial sums
// atomicAdd'ed into pre-zeroed out; finalize quantizes in place.
// ADC bits identical to verified R1-R7; v2f epilogue is R5's bit-exact form.
// ---------------------------------------------------------------------------
__global__ __launch_bounds__(256, 4) void cim_mfma(
    const uint8_t* __restrict__ Ap2, const uint8_t* __restrict__ Bp,
    const uint32_t* __restrict__ flags, float* __restrict__ out)
{
    const float MAG = 12582912.0f;                  // 2^23 + 2^22
    int tid = threadIdx.x, wid = tid >> 6, l = tid & 63, h2 = l >> 5;

    // ---- LPT worklist: rank pairs by (popcount desc, index asc) ----
    uint32_t f0 = flags[l], f1 = flags[64 + l];
    int pc0 = __popc(f0), pc1 = __popc(f1);
    int total = __popcll(__ballot(pc0 > 0)) + __popcll(__ballot(pc1 > 0));
    int idx = blockIdx.x >> 2, z = blockIdx.x & 3;
    if (idx >= total) return;
    unsigned long long lt = (1ULL << l) - 1;
    int rank0 = 0, rank1 = 0;
    #pragma unroll
    for (int v = 16; v >= 1; --v) {
        unsigned long long m0 = __ballot(pc0 == v);
        unsigned long long m1 = __ballot(pc1 == v);
        int c = __popcll(m0) + __popcll(m1);
        rank0 += (pc0 < v) ? c : ((pc0 == v) ? __popcll(m0 & lt) : 0);
        rank1 += (pc1 < v) ? c : ((pc1 == v) ? (__popcll(m0) + __popcll(m1 & lt)) : 0);
    }
    unsigned long long s0 = __ballot(rank0 == idx);
    unsigned long long s1 = __ballot(rank1 == idx);
    int p = s0 ? __builtin_ctzll(s0) : (64 + __builtin_ctzll(s1));
    int sgs = p >> 3, ob = p & 7;
    uint32_t fb = flags[p];

    int y = blockIdx.y;
    int s = sgs & 7, sg = sgs >> 3;
    int col = sgs * 1024 + ob * 128 + wid * 32 + (l & 31);
    float clane = ldexpf(192.0f / 255.0f, 14 - 2 * s);   // step * 4^(7-s)
    if (sg) clane = -clane;

    v2f acc2[8];
    #pragma unroll
    for (int i = 0; i < 8; ++i) acc2[i] = (v2f)0.0f;
    v16i zero;
    #pragma unroll
    for (int i = 0; i < 16; ++i) zero[i] = 0;

    int rank = 0, nproc = 0;
    for (int r = 0; r < RT; ++r) {
        if (!((fb >> r) & 1u)) continue;            // uniform skip, exact
        if ((rank++ & 3) != z) continue;            // 4-way r-split
        ++nproc;

        v4i bf0 = *(const v4i*)(Bp + ((size_t)(r * 4 + h2)     * NCOL + col) * 16);
        v4i bf1 = *(const v4i*)(Bp + ((size_t)(r * 4 + 2 + h2) * NCOL + col) * 16);

        const uint8_t* abase = Ap2 + ((size_t)(r * 8 + y) * 16) * 2048 + l * 16;
        #pragma unroll 4
        for (int t = 0; t < STN; ++t) {
            const uint8_t* ap = abase + t * 2048;
            v4i af0 = *(const v4i*)ap;              // coalesced 1KB/wave
            v4i af1 = *(const v4i*)(ap + 1024);
            v16i c = __builtin_amdgcn_mfma_i32_32x32x32_i8(af0, bf0, zero, 0, 0, 0);
            c      = __builtin_amdgcn_mfma_i32_32x32x32_i8(af1, bf1, c,    0, 0, 0);
            float wt = (t == 15) ? -32768.0f : (float)(1 << t);
            float cw = clane * wt;                  // exact pow2 scale
            #pragma unroll
            for (int i = 0; i < 8; ++i) {
                v2f af; af.x = (float)c[2 * i]; af.y = (float)c[2 * i + 1];
                v2f tq;
                tq.x = fmaf(af.x, 1.328125f, MAG);  // exact product; add rounds
                tq.y = fmaf(af.y, 1.328125f, MAG);  //   half-even == rintf
                v2f qf = tq - MAG;                  // Sterbenz-exact
                acc2[i].x = fmaf(qf.x, cw, acc2[i].x);
                acc2[i].y = fmaf(qf.y, cw, acc2[i].y);
            }
        }
    }

    if (nproc == 0) return;                         // contributed nothing
    int o = ob * 128 + wid * 32 + (l & 31);
    #pragma unroll
    for (int i = 0; i < 16; ++i) {
        int b = y * 32 + (i & 3) + 8 * (i >> 2) + 4 * h2;   // C/D row map
        float v = (i & 1) ? acc2[i >> 1].y : acc2[i >> 1].x;
        atomicAdd(&out[(size_t)b * OUT_F + o], v);
    }
}

// ---------------------------------------------------------------------------
// In-place finalize: scale, ACM quantize, add bias.
// ---------------------------------------------------------------------------
__global__ __launch_bounds__(256) void finalize(
    float* __restrict__ out, const float* __restrict__ bias)
{
    int idx = blockIdx.x * 256 + threadIdx.x;
    int o = idx & (OUT_F - 1);
    float ov = out[idx] * 0x1p-24f;
    float q = rintf(ov * 4096.0f);
    q = fminf(fmaxf(q, -32768.0f), 32767.0f);
    out[idx] = q * 0x1p-12f + bias[o];
}

// ---------------------------------------------------------------------------
extern "C" void kernel_launch(void* const* d_in, const int* in_sizes, int n_in,
                              void* d_out, int out_size, void* d_ws, size_t ws_size,
                              hipStream_t stream) {
    const float* x    = (const float*)d_in[0];
    const float* w    = (const float*)d_in[1];
    const float* bias = (const float*)d_in[2];
    float* out = (float*)d_out;

    uint8_t*  Ap2   = (uint8_t*)d_ws;
    uint8_t*  Bp    = Ap2 + AP_SZ;
    uint32_t* flags = (uint32_t*)(Bp + BP_SZ);

    hipMemsetAsync(flags, 0, 128 * sizeof(uint32_t), stream);
    hipMemsetAsync(out, 0, (size_t)BATCH * OUT_F * sizeof(float), stream);
    hipLaunchKernelGGL(pack_fused, dim3(768), dim3(256), 0, stream,
                       x, w, Ap2, Bp, flags);
    hipLaunchKernelGGL(cim_mfma, dim3(512, 8), dim3(256), 0, stream,
                       Ap2, Bp, flags, out);
    hipLaunchKernelGGL(finalize, dim3(BATCH * OUT_F / 256), dim3(256), 0, stream,
                       out, bias);
}